// Round 1
// baseline (371.857 us; speedup 1.0000x reference)
//
#include <hip/hip_runtime.h>
#include <hip/hip_bf16.h>
#include <math.h>

#define Sd 8
#define Bd 1024
#define Ed 768
#define Hd 12
#define Dd 64
#define SBd 8192

typedef short bf16x8 __attribute__((ext_vector_type(8)));
typedef unsigned short u16x8 __attribute__((ext_vector_type(8)));
typedef float f32x4 __attribute__((ext_vector_type(4)));

static __device__ __forceinline__ unsigned short f2bf(float f) {
  unsigned int u = __builtin_bit_cast(unsigned int, f);
  u += 0x7fffu + ((u >> 16) & 1u);
  return (unsigned short)(u >> 16);
}

// ---------------------------------------------------------------------------
// QKV projection: OUT[i,j] = sum_e X[i,e]*W[j,e] + bias[j]
// X: (8192,768) f32, W: (768,768) f32 row-major (rows = output features)
// out: bf16 in [s][h][b][d] layout.  grid (128, 12, 3), block 256.
// ---------------------------------------------------------------------------
__global__ __launch_bounds__(256) void qkv_kernel(
    const float* __restrict__ Qin, const float* __restrict__ Kin,
    const float* __restrict__ Vin,
    const float* __restrict__ Wq, const float* __restrict__ bq,
    const float* __restrict__ Wk, const float* __restrict__ bk,
    const float* __restrict__ Wv, const float* __restrict__ bv,
    unsigned short* __restrict__ qo, unsigned short* __restrict__ ko,
    unsigned short* __restrict__ vo) {
  __shared__ unsigned short As[64 * 72];
  __shared__ unsigned short Bs[64 * 72];
  const float* X;
  const float* W;
  const float* bias;
  unsigned short* out;
  switch (blockIdx.z) {
    case 0: X = Qin; W = Wq; bias = bq; out = qo; break;
    case 1: X = Kin; W = Wk; bias = bk; out = ko; break;
    default: X = Vin; W = Wv; bias = bv; out = vo; break;
  }
  const int i0 = blockIdx.x * 64;
  const int j0 = blockIdx.y * 64;
  const int t = threadIdx.x;
  const int w = t >> 6, l = t & 63, lr = l & 15, lg = l >> 4;
  const int srow = t >> 2, skg = (t & 3) << 4;

  f32x4 acc[4] = {};

  for (int k0 = 0; k0 < Ed; k0 += 64) {
    const float* xp = X + (size_t)(i0 + srow) * Ed + k0 + skg;
    const float* wp = W + (size_t)(j0 + srow) * Ed + k0 + skg;
    float4 x0 = *(const float4*)xp;
    float4 x1 = *(const float4*)(xp + 4);
    float4 x2 = *(const float4*)(xp + 8);
    float4 x3 = *(const float4*)(xp + 12);
    float4 w0 = *(const float4*)wp;
    float4 w1 = *(const float4*)(wp + 4);
    float4 w2 = *(const float4*)(wp + 8);
    float4 w3 = *(const float4*)(wp + 12);
    u16x8 pa0, pa1, pb0, pb1;
    pa0[0] = f2bf(x0.x); pa0[1] = f2bf(x0.y); pa0[2] = f2bf(x0.z); pa0[3] = f2bf(x0.w);
    pa0[4] = f2bf(x1.x); pa0[5] = f2bf(x1.y); pa0[6] = f2bf(x1.z); pa0[7] = f2bf(x1.w);
    pa1[0] = f2bf(x2.x); pa1[1] = f2bf(x2.y); pa1[2] = f2bf(x2.z); pa1[3] = f2bf(x2.w);
    pa1[4] = f2bf(x3.x); pa1[5] = f2bf(x3.y); pa1[6] = f2bf(x3.z); pa1[7] = f2bf(x3.w);
    pb0[0] = f2bf(w0.x); pb0[1] = f2bf(w0.y); pb0[2] = f2bf(w0.z); pb0[3] = f2bf(w0.w);
    pb0[4] = f2bf(w1.x); pb0[5] = f2bf(w1.y); pb0[6] = f2bf(w1.z); pb0[7] = f2bf(w1.w);
    pb1[0] = f2bf(w2.x); pb1[1] = f2bf(w2.y); pb1[2] = f2bf(w2.z); pb1[3] = f2bf(w2.w);
    pb1[4] = f2bf(w3.x); pb1[5] = f2bf(w3.y); pb1[6] = f2bf(w3.z); pb1[7] = f2bf(w3.w);
    __syncthreads();
    *(u16x8*)&As[srow * 72 + skg] = pa0;
    *(u16x8*)&As[srow * 72 + skg + 8] = pa1;
    *(u16x8*)&Bs[srow * 72 + skg] = pb0;
    *(u16x8*)&Bs[srow * 72 + skg + 8] = pb1;
    __syncthreads();
#pragma unroll
    for (int ks = 0; ks < 2; ++ks) {
      bf16x8 a = *(const bf16x8*)&As[(w * 16 + lr) * 72 + ks * 32 + lg * 8];
#pragma unroll
      for (int ct = 0; ct < 4; ++ct) {
        bf16x8 bb = *(const bf16x8*)&Bs[(ct * 16 + lr) * 72 + ks * 32 + lg * 8];
        acc[ct] = __builtin_amdgcn_mfma_f32_16x16x32_bf16(a, bb, acc[ct], 0, 0, 0);
      }
    }
  }

  const int h = j0 >> 6;  // j0 is a multiple of 64, one head per N-tile
#pragma unroll
  for (int ct = 0; ct < 4; ++ct) {
#pragma unroll
    for (int r = 0; r < 4; ++r) {
      int i = i0 + w * 16 + lg * 4 + r;
      int d = ct * 16 + lr;
      float v = acc[ct][r] + bias[h * 64 + d];
      int s = i >> 10, b = i & 1023;
      out[((((size_t)s * Hd + h) * Bd + b) << 6) + d] = f2bf(v);
    }
  }
}

// ---------------------------------------------------------------------------
// Attention per (s,h): scores = q k^T / 8, softmax (2-pass, recompute),
// write attn f32, accumulate ctx = P V -> bf16 ws.  grid (16, 96), block 256.
// ---------------------------------------------------------------------------
__global__ __launch_bounds__(256) void attn_kernel(
    const unsigned short* __restrict__ qb, const unsigned short* __restrict__ kb,
    const unsigned short* __restrict__ vb, float* __restrict__ attn_out,
    unsigned short* __restrict__ ctx_out) {
  __shared__ unsigned short Ks[64 * 72];
  __shared__ unsigned short Vt[64 * 72];
  __shared__ unsigned short Pb[4][16 * 72];
  const int sh = blockIdx.y;
  const int s = sh / Hd, h = sh % Hd;
  const int row0 = blockIdx.x * 64;
  const size_t base = (size_t)sh * Bd * 64;
  const int t = threadIdx.x;
  const int w = t >> 6, l = t & 63, lr = l & 15, lg = l >> 4;
  const int sc_ = t >> 2, sdg = (t & 3) << 4;

  // Q fragments for this wave's 16 rows
  const int qrow = row0 + w * 16 + lr;
  const bf16x8 aq0 = *(const bf16x8*)(qb + base + (size_t)qrow * 64 + lg * 8);
  const bf16x8 aq1 = *(const bf16x8*)(qb + base + (size_t)qrow * 64 + 32 + lg * 8);

  float m[4], lsum[4];
#pragma unroll
  for (int r = 0; r < 4; ++r) { m[r] = -1e30f; lsum[r] = 0.0f; }

  // ---- pass 1: row max + denom (online) ----
  for (int ct = 0; ct < 16; ++ct) {
    const unsigned short* kp = kb + base + (size_t)(ct * 64 + sc_) * 64 + sdg;
    u16x8 k0 = *(const u16x8*)kp;
    u16x8 k1 = *(const u16x8*)(kp + 8);
    __syncthreads();
    *(u16x8*)&Ks[sc_ * 72 + sdg] = k0;
    *(u16x8*)&Ks[sc_ * 72 + sdg + 8] = k1;
    __syncthreads();
    f32x4 scv[4] = {};
#pragma unroll
    for (int ks = 0; ks < 2; ++ks) {
      bf16x8 a = (ks == 0) ? aq0 : aq1;
#pragma unroll
      for (int ct2 = 0; ct2 < 4; ++ct2) {
        bf16x8 bb = *(const bf16x8*)&Ks[(ct2 * 16 + lr) * 72 + ks * 32 + lg * 8];
        scv[ct2] = __builtin_amdgcn_mfma_f32_16x16x32_bf16(a, bb, scv[ct2], 0, 0, 0);
      }
    }
#pragma unroll
    for (int ct2 = 0; ct2 < 4; ++ct2)
#pragma unroll
      for (int r = 0; r < 4; ++r) scv[ct2][r] *= 0.125f;
#pragma unroll
    for (int r = 0; r < 4; ++r) {
      float v = fmaxf(fmaxf(scv[0][r], scv[1][r]), fmaxf(scv[2][r], scv[3][r]));
      v = fmaxf(v, __shfl_xor(v, 1, 16));
      v = fmaxf(v, __shfl_xor(v, 2, 16));
      v = fmaxf(v, __shfl_xor(v, 4, 16));
      v = fmaxf(v, __shfl_xor(v, 8, 16));
      float mn = fmaxf(m[r], v);
      float ss = expf(scv[0][r] - mn) + expf(scv[1][r] - mn) +
                 expf(scv[2][r] - mn) + expf(scv[3][r] - mn);
      ss += __shfl_xor(ss, 1, 16);
      ss += __shfl_xor(ss, 2, 16);
      ss += __shfl_xor(ss, 4, 16);
      ss += __shfl_xor(ss, 8, 16);
      lsum[r] = lsum[r] * expf(m[r] - mn) + ss;
      m[r] = mn;
    }
  }

  float invl[4];
#pragma unroll
  for (int r = 0; r < 4; ++r) invl[r] = 1.0f / lsum[r];

  // ---- pass 2: recompute scores, write attn, accumulate PV ----
  f32x4 cacc[4] = {};
  for (int ct = 0; ct < 16; ++ct) {
    const unsigned short* kp = kb + base + (size_t)(ct * 64 + sc_) * 64 + sdg;
    const unsigned short* vp = vb + base + (size_t)(ct * 64 + sc_) * 64 + sdg;
    u16x8 k0 = *(const u16x8*)kp;
    u16x8 k1 = *(const u16x8*)(kp + 8);
    u16x8 v0 = *(const u16x8*)vp;
    u16x8 v1 = *(const u16x8*)(vp + 8);
    __syncthreads();
    *(u16x8*)&Ks[sc_ * 72 + sdg] = k0;
    *(u16x8*)&Ks[sc_ * 72 + sdg + 8] = k1;
#pragma unroll
    for (int jj = 0; jj < 8; ++jj) {
      Vt[(sdg + jj) * 72 + sc_] = (unsigned short)v0[jj];
      Vt[(sdg + 8 + jj) * 72 + sc_] = (unsigned short)v1[jj];
    }
    __syncthreads();
    f32x4 scv[4] = {};
#pragma unroll
    for (int ks = 0; ks < 2; ++ks) {
      bf16x8 a = (ks == 0) ? aq0 : aq1;
#pragma unroll
      for (int ct2 = 0; ct2 < 4; ++ct2) {
        bf16x8 bb = *(const bf16x8*)&Ks[(ct2 * 16 + lr) * 72 + ks * 32 + lg * 8];
        scv[ct2] = __builtin_amdgcn_mfma_f32_16x16x32_bf16(a, bb, scv[ct2], 0, 0, 0);
      }
    }
#pragma unroll
    for (int ct2 = 0; ct2 < 4; ++ct2) {
#pragma unroll
      for (int r = 0; r < 4; ++r) {
        float p = expf(scv[ct2][r] * 0.125f - m[r]) * invl[r];
        int row = row0 + w * 16 + lg * 4 + r;
        int col = ct * 64 + ct2 * 16 + lr;
        attn_out[((size_t)sh * Bd + row) * Bd + col] = p;
        Pb[w][(lg * 4 + r) * 72 + ct2 * 16 + lr] = f2bf(p);
      }
    }
#pragma unroll
    for (int ks2 = 0; ks2 < 2; ++ks2) {
      bf16x8 pa = *(const bf16x8*)&Pb[w][lr * 72 + ks2 * 32 + lg * 8];
#pragma unroll
      for (int dt = 0; dt < 4; ++dt) {
        bf16x8 bv = *(const bf16x8*)&Vt[(dt * 16 + lr) * 72 + ks2 * 32 + lg * 8];
        cacc[dt] = __builtin_amdgcn_mfma_f32_16x16x32_bf16(pa, bv, cacc[dt], 0, 0, 0);
      }
    }
    __syncthreads();
  }

#pragma unroll
  for (int dt = 0; dt < 4; ++dt) {
#pragma unroll
    for (int r = 0; r < 4; ++r) {
      int row = row0 + w * 16 + lg * 4 + r;
      size_t i = (size_t)s * Bd + row;
      int j = h * 64 + dt * 16 + lr;
      ctx_out[i * Ed + j] = f2bf(cacc[dt][r]);
    }
  }
}

// ---------------------------------------------------------------------------
// Output projection: x[i,j] = sum_k ctx[i,k]*Wo[j,k] + bo[j] + Q[i,j]
// ctx bf16 (8192,768), Wo f32 (768,768). x -> f32 ws. grid (128,12), block 256
// ---------------------------------------------------------------------------
__global__ __launch_bounds__(256) void proj_kernel(
    const unsigned short* __restrict__ ctx, const float* __restrict__ Wo,
    const float* __restrict__ bo, const float* __restrict__ Qin,
    float* __restrict__ xout) {
  __shared__ unsigned short As[64 * 72];
  __shared__ unsigned short Bs[64 * 72];
  const int i0 = blockIdx.x * 64;
  const int j0 = blockIdx.y * 64;
  const int t = threadIdx.x;
  const int w = t >> 6, l = t & 63, lr = l & 15, lg = l >> 4;
  const int srow = t >> 2, skg = (t & 3) << 4;

  f32x4 acc[4] = {};

  for (int k0 = 0; k0 < Ed; k0 += 64) {
    const unsigned short* ap = ctx + (size_t)(i0 + srow) * Ed + k0 + skg;
    u16x8 a0 = *(const u16x8*)ap;
    u16x8 a1 = *(const u16x8*)(ap + 8);
    const float* wp = Wo + (size_t)(j0 + srow) * Ed + k0 + skg;
    float4 w0 = *(const float4*)wp;
    float4 w1 = *(const float4*)(wp + 4);
    float4 w2 = *(const float4*)(wp + 8);
    float4 w3 = *(const float4*)(wp + 12);
    u16x8 pb0, pb1;
    pb0[0] = f2bf(w0.x); pb0[1] = f2bf(w0.y); pb0[2] = f2bf(w0.z); pb0[3] = f2bf(w0.w);
    pb0[4] = f2bf(w1.x); pb0[5] = f2bf(w1.y); pb0[6] = f2bf(w1.z); pb0[7] = f2bf(w1.w);
    pb1[0] = f2bf(w2.x); pb1[1] = f2bf(w2.y); pb1[2] = f2bf(w2.z); pb1[3] = f2bf(w2.w);
    pb1[4] = f2bf(w3.x); pb1[5] = f2bf(w3.y); pb1[6] = f2bf(w3.z); pb1[7] = f2bf(w3.w);
    __syncthreads();
    *(u16x8*)&As[srow * 72 + skg] = a0;
    *(u16x8*)&As[srow * 72 + skg + 8] = a1;
    *(u16x8*)&Bs[srow * 72 + skg] = pb0;
    *(u16x8*)&Bs[srow * 72 + skg + 8] = pb1;
    __syncthreads();
#pragma unroll
    for (int ks = 0; ks < 2; ++ks) {
      bf16x8 a = *(const bf16x8*)&As[(w * 16 + lr) * 72 + ks * 32 + lg * 8];
#pragma unroll
      for (int ct = 0; ct < 4; ++ct) {
        bf16x8 bb = *(const bf16x8*)&Bs[(ct * 16 + lr) * 72 + ks * 32 + lg * 8];
        acc[ct] = __builtin_amdgcn_mfma_f32_16x16x32_bf16(a, bb, acc[ct], 0, 0, 0);
      }
    }
  }

#pragma unroll
  for (int ct = 0; ct < 4; ++ct) {
#pragma unroll
    for (int r = 0; r < 4; ++r) {
      int i = i0 + w * 16 + lg * 4 + r;
      int j = j0 + ct * 16 + lr;
      float v = acc[ct][r] + bo[j] + Qin[(size_t)i * Ed + j];
      xout[(size_t)i * Ed + j] = v;
    }
  }
}

// ---------------------------------------------------------------------------
// Row LayerNorm over E=768.  grid (8192), block 256.
// ---------------------------------------------------------------------------
__global__ __launch_bounds__(256) void ln_kernel(
    const float* __restrict__ x, const float* __restrict__ g,
    const float* __restrict__ bb, float* __restrict__ out) {
  const int i = blockIdx.x;
  const int t = threadIdx.x;
  const float* xr = x + (size_t)i * Ed;
  float v0 = xr[t], v1 = xr[t + 256], v2 = xr[t + 512];
  float s1 = v0 + v1 + v2;
  float s2 = v0 * v0 + v1 * v1 + v2 * v2;
#pragma unroll
  for (int mk = 1; mk < 64; mk <<= 1) {
    s1 += __shfl_xor(s1, mk, 64);
    s2 += __shfl_xor(s2, mk, 64);
  }
  __shared__ float red[8];
  const int w = t >> 6, l = t & 63;
  if (l == 0) { red[w] = s1; red[w + 4] = s2; }
  __syncthreads();
  s1 = red[0] + red[1] + red[2] + red[3];
  s2 = red[4] + red[5] + red[6] + red[7];
  float mu = s1 * (1.0f / 768.0f);
  float var = s2 * (1.0f / 768.0f) - mu * mu;
  float rs = rsqrtf(var + 1e-5f);
  float* orow = out + (size_t)i * Ed;
  orow[t] = (v0 - mu) * rs * g[t] + bb[t];
  orow[t + 256] = (v1 - mu) * rs * g[t + 256] + bb[t + 256];
  orow[t + 512] = (v2 - mu) * rs * g[t + 512] + bb[t + 512];
}

extern "C" void kernel_launch(void* const* d_in, const int* in_sizes, int n_in,
                              void* d_out, int out_size, void* d_ws, size_t ws_size,
                              hipStream_t stream) {
  (void)in_sizes; (void)n_in; (void)out_size; (void)ws_size;
  const float* Qin = (const float*)d_in[0];
  const float* Kin = (const float*)d_in[1];
  const float* Vin = (const float*)d_in[2];
  const float* Wq = (const float*)d_in[3];
  const float* bq = (const float*)d_in[4];
  const float* Wk = (const float*)d_in[5];
  const float* bk = (const float*)d_in[6];
  const float* Wv = (const float*)d_in[7];
  const float* bv = (const float*)d_in[8];
  const float* Wo = (const float*)d_in[9];
  const float* bo = (const float*)d_in[10];
  const float* ln_g = (const float*)d_in[11];
  const float* ln_b = (const float*)d_in[12];

  float* outp = (float*)d_out;
  float* normed = outp;
  float* attn_out = outp + (size_t)SBd * Ed;  // 6291456 elements in

  char* ws = (char*)d_ws;
  unsigned short* qws = (unsigned short*)ws;
  unsigned short* kws = qws + 6291456;
  unsigned short* vws = kws + 6291456;
  unsigned short* ctxws = vws + 6291456;
  float* xws = (float*)(ws + (size_t)4 * 12582912);

  dim3 blk(256);
  hipLaunchKernelGGL(qkv_kernel, dim3(128, 12, 3), blk, 0, stream,
                     Qin, Kin, Vin, Wq, bq, Wk, bk, Wv, bv, qws, kws, vws);
  hipLaunchKernelGGL(attn_kernel, dim3(16, 96), blk, 0, stream,
                     qws, kws, vws, attn_out, ctxws);
  hipLaunchKernelGGL(proj_kernel, dim3(128, 12), blk, 0, stream,
                     ctxws, Wo, bo, Qin, xws);
  hipLaunchKernelGGL(ln_kernel, dim3(8192), blk, 0, stream,
                     xws, ln_g, ln_b, normed);
}